// Round 17
// baseline (610.541 us; speedup 1.0000x reference)
//
#include <hip/hip_runtime.h>

// GlobalInteraction r17: B=4096, N_GLOBAL=64, D=256, E=4, TPE=16, F=4096
// X:(B,64,256) f32; W1:(E,4096,256); b1:(E,256); W2:(E,256,4096); b2:(E,4096);
// gamma,beta:(E,256). Out:(B,64,256) f32.
//
// r17 = r16 + gemm2 refill fix: grid 2048 -> 4096 (one 64-row m-tile per
// block; continuous block refill = memory parallelism, the r16 lesson), plus
// nontemporal Out stores (write-once, never read) and nontemporal Y0b loads
// (read-once) to keep L3 for Y0b/HP/W2P. fused_ag/packs: r16 verbatim.

typedef __attribute__((ext_vector_type(4))) float f32x4;
typedef __bf16 bf16;
typedef __attribute__((ext_vector_type(8))) bf16 bf16x8;
typedef __attribute__((ext_vector_type(4))) bf16 bf16x4;
typedef __attribute__((ext_vector_type(2))) bf16 bf16x2;

#define DEV static __device__ __forceinline__

DEV f32x4 zero4() { return f32x4{0.f, 0.f, 0.f, 0.f}; }

DEV bf16x8 cvt8(const f32x4& a, const f32x4& b) {
  bf16x8 o;
  o[0] = (bf16)a.x; o[1] = (bf16)a.y; o[2] = (bf16)a.z; o[3] = (bf16)a.w;
  o[4] = (bf16)b.x; o[5] = (bf16)b.y; o[6] = (bf16)b.z; o[7] = (bf16)b.w;
  return o;
}

// ---------------------------------------------------------------------------
// pack_w1: W1 (E,4096,256) f32 -> fragment-packed bf16.
// ---------------------------------------------------------------------------
__global__ __launch_bounds__(256) void pack_w1(const float* __restrict__ W1,
                                               bf16* __restrict__ P) {
  const int e = blockIdx.z, kc = blockIdx.y;
  const int nf = blockIdx.x * 4 + (threadIdx.x >> 6);
  const int l = threadIdx.x & 63;
  const float* src = W1 + (size_t)e * 4096 * 256 +
                     (size_t)(kc * 32 + (l >> 4) * 8) * 256 + nf * 16 + (l & 15);
  bf16x8 o;
#pragma unroll
  for (int j = 0; j < 8; j++) o[j] = (bf16)src[(size_t)j * 256];
  *(bf16x8*)&P[(((size_t)e * 128 + kc) * 16 + nf) * 512 + l * 8] = o;
}

// ---------------------------------------------------------------------------
// pack_w2: W2 (E,256,4096) f32 -> fragment-packed bf16.
// ---------------------------------------------------------------------------
__global__ __launch_bounds__(256) void pack_w2(const float* __restrict__ W2,
                                               bf16* __restrict__ P) {
  const int e = blockIdx.z, t = blockIdx.y, kc = blockIdx.x;
  const int l = threadIdx.x & 63;
#pragma unroll
  for (int it = 0; it < 4; it++) {
    int nfl = it * 4 + (threadIdx.x >> 6);
    const float* src = W2 + (size_t)e * 256 * 4096 +
                       (size_t)(kc * 32 + (l >> 4) * 8) * 4096 + t * 256 +
                       nfl * 16 + (l & 15);
    bf16x8 o;
#pragma unroll
    for (int j = 0; j < 8; j++) o[j] = (bf16)src[(size_t)j * 4096];
    *(bf16x8*)&P[(((size_t)e * 256 + t * 16 + nfl) * 8 + kc) * 512 + l * 8] = o;
  }
}

// ---------------------------------------------------------------------------
// fused_ag (r16): blocks 0-511 gemm1; blocks 512-4607 attention (1 pair/wave).
// ---------------------------------------------------------------------------
__global__ __launch_bounds__(256) void fused_ag(
    const float* __restrict__ X, const bf16* __restrict__ W1P,
    const float* __restrict__ b1, float* __restrict__ Y0f,
    bf16* __restrict__ Y0b, bf16* __restrict__ HP, int useBf) {
  __shared__ __align__(16) bf16 S[4 * 4608];   // 36,864 B
  __shared__ __align__(16) bf16 Plw[4 * 256];  //  2,048 B (P cols 0..15)
  __shared__ __align__(16) bf16 Zb[8];         //     16 B (zero k-pad)
  const int tid = threadIdx.x, lane = tid & 63, w = tid >> 6;
  const int lr = lane & 15, g = lane >> 4;
  const int fid = blockIdx.x;                  // 4608 blocks

  if (fid >= 512) {
    // ================= attention blocks: 1 pair per wave ==================
    bf16* xt = &S[w * 4608];
    bf16* plw = &Plw[w * 256];
    if (tid < 8) Zb[tid] = (bf16)0.f;
    __syncthreads();  // Zb visible to all waves
    const int koff = (g & 1) * 8;  // g>=2 lanes broadcast-read g&1's address

    const int p = (fid - 512) * 4 + w;         // pair id 0..16383
    const int b = p >> 2, e = p & 3;
    const size_t obase0 = (size_t)b * 16384 + e * 4096;
    const float* Xb = X + obase0;

    bf16x8 af[8];
#pragma unroll
    for (int c = 0; c < 8; c++) {
      const float* qq = Xb + lr * 256 + c * 32 + g * 8;
      f32x4 v0 = *(const f32x4*)qq;
      f32x4 v1 = *(const f32x4*)(qq + 4);
      bf16x8 o = cvt8(v0, v1);
      af[c] = o;
#pragma unroll
      for (int j = 0; j < 8; j++)
        xt[(c * 32 + g * 8 + j) * 18 + lr] = o[j];  // conflict-free
    }

    f32x4 s = zero4();
#pragma unroll
    for (int c = 0; c < 8; c++)
      s = __builtin_amdgcn_mfma_f32_16x16x32_bf16(af[c], af[c], s, 0, 0, 0);

    // softmax rows t=4g+r over m=lr; residual folded in: P' = P + I
    float pv[4];
#pragma unroll
    for (int r = 0; r < 4; r++) {
      float v = s[r] * 0.0625f;
      float mx = v;
#pragma unroll
      for (int mm = 1; mm < 16; mm <<= 1) mx = fmaxf(mx, __shfl_xor(mx, mm));
      float ev = __expf(v - mx);
      float sum = ev;
#pragma unroll
      for (int mm = 1; mm < 16; mm <<= 1) sum += __shfl_xor(sum, mm);
      pv[r] = ev / sum + ((lr == g * 4 + r) ? 1.0f : 0.0f);
    }
#pragma unroll
    for (int r = 0; r < 4; r++) plw[(g * 4 + r) * 16 + lr] = (bf16)pv[r];
    const bf16* psrc = (g < 2) ? &plw[lr * 16 + g * 8] : &Zb[0];
    bf16x8 pf = *(const bf16x8*)psrc;

    // PV: Y0 = (P+I) @ Xp
    float yo[16][4];
#pragma unroll
    for (int nc = 0; nc < 16; nc++) {
      const bf16* rowp = &xt[(nc * 16 + lr) * 18];
      bf16x8 bfr;
#pragma unroll
      for (int h = 0; h < 4; h++) {
        bf16x2 tv = *(const bf16x2*)&rowp[koff + h * 2];
        bfr[2 * h] = tv[0];
        bfr[2 * h + 1] = tv[1];
      }
      f32x4 xd =
          __builtin_amdgcn_mfma_f32_16x16x32_bf16(pf, bfr, zero4(), 0, 0, 0);
      yo[nc][0] = xd[0];
      yo[nc][1] = xd[1];
      yo[nc][2] = xd[2];
      yo[nc][3] = xd[3];
    }

    // transpose via LDS overlay Yl[16][268] (conflict-free scalar writes)
#pragma unroll
    for (int nc = 0; nc < 16; nc++)
#pragma unroll
      for (int r = 0; r < 4; r++)
        xt[(g * 4 + r) * 268 + nc * 16 + lr] = (bf16)yo[nc][r];

    const int tok = lane >> 2, cc = lane & 3;
    if (useBf) {
#pragma unroll
      for (int i = 0; i < 8; i++) {
        int d0 = i * 32 + cc * 8;
        bf16x4 v0 = *(const bf16x4*)&xt[tok * 268 + d0];
        bf16x4 v1 = *(const bf16x4*)&xt[tok * 268 + d0 + 4];
        bf16x8 v;
        v[0] = v0[0]; v[1] = v0[1]; v[2] = v0[2]; v[3] = v0[3];
        v[4] = v1[0]; v[5] = v1[1]; v[6] = v1[2]; v[7] = v1[3];
        *(bf16x8*)&Y0b[obase0 + tok * 256 + d0] = v;
      }
    } else {
#pragma unroll
      for (int i = 0; i < 8; i++) {
        int d0 = i * 32 + cc * 8;
        bf16x4 v0 = *(const bf16x4*)&xt[tok * 268 + d0];
        bf16x4 v1 = *(const bf16x4*)&xt[tok * 268 + d0 + 4];
        f32x4 a, bb;
        a.x = (float)v0[0]; a.y = (float)v0[1];
        a.z = (float)v0[2]; a.w = (float)v0[3];
        bb.x = (float)v1[0]; bb.y = (float)v1[1];
        bb.z = (float)v1[2]; bb.w = (float)v1[3];
        *(f32x4*)&Y0f[obase0 + tok * 256 + d0] = a;
        *(f32x4*)&Y0f[obase0 + tok * 256 + d0 + 4] = bb;
      }
    }
  } else {
    // ================= gemm1 blocks: M=32, BK=128, 4 waves =================
    const int sub = fid;                         // 0..511
    const int e = (sub & 7) >> 1;                // expert per XCD-pair
    const int m = ((sub >> 3) << 1) | (sub & 1); // 0..127
    const int b0 = m * 32;
    bf16* Ab0 = S;           // [32*136]
    bf16* Ab1 = S + 4352;    // [32*136]
    const int arow = tid >> 3, ak0 = (tid & 7) * 16;
    const size_t abase = (size_t)(b0 + arow) * 16384 + e * 4096 + ak0;
    const bf16* Wp = W1P + (size_t)e * 128 * 16 * 512;

    f32x4 acc[2][4];
#pragma unroll
    for (int i = 0; i < 2; i++)
#pragma unroll
      for (int j = 0; j < 4; j++) acc[i][j] = zero4();

    f32x4 p0, p1, p2, p3;
    {
      const float* q = X + abase;
      p0 = *(const f32x4*)q;       p1 = *(const f32x4*)(q + 4);
      p2 = *(const f32x4*)(q + 8); p3 = *(const f32x4*)(q + 12);
    }

    for (int kt = 0; kt < 32; kt++) {
      bf16* Ac = (kt & 1) ? Ab1 : Ab0;
      *(bf16x8*)&Ac[arow * 136 + ak0] = cvt8(p0, p1);
      *(bf16x8*)&Ac[arow * 136 + ak0 + 8] = cvt8(p2, p3);
      if (kt < 31) {
        const float* q = X + abase + (kt + 1) * 128;
        p0 = *(const f32x4*)q;       p1 = *(const f32x4*)(q + 4);
        p2 = *(const f32x4*)(q + 8); p3 = *(const f32x4*)(q + 12);
      }
      __syncthreads();  // block-uniform branch: all threads reach this
#pragma unroll
      for (int kki = 0; kki < 4; kki++) {
        const int kc = kt * 4 + kki;
        bf16x8 afr[2], bfr[4];
#pragma unroll
        for (int i = 0; i < 2; i++)
          afr[i] = *(const bf16x8*)&Ac[(i * 16 + lr) * 136 + kki * 32 + g * 8];
#pragma unroll
        for (int j = 0; j < 4; j++)
          bfr[j] = *(const bf16x8*)&Wp[(((size_t)kc) * 16 + w * 4 + j) * 512 +
                                       lane * 8];
#pragma unroll
        for (int i = 0; i < 2; i++)
#pragma unroll
          for (int j = 0; j < 4; j++)
            acc[i][j] = __builtin_amdgcn_mfma_f32_16x16x32_bf16(
                afr[i], bfr[j], acc[i][j], 0, 0, 0);
      }
    }
    // epilogue: relu(acc + b1) -> HP (fragment-packed)
#pragma unroll
    for (int j = 0; j < 4; j++) {
      const int col = w * 64 + j * 16 + lr;
      const float bv = b1[e * 256 + col];
      const int kc = col >> 5, lhi = (col >> 3) & 3, jj = col & 7;
#pragma unroll
      for (int i = 0; i < 2; i++) {
        const int mfg = m * 2 + i;
        bf16* dst = HP + (((size_t)e * 256 + mfg) * 8 + kc) * 512 + jj;
#pragma unroll
        for (int r = 0; r < 4; r++) {
          float v = fmaxf(acc[i][j][r] + bv, 0.f);
          dst[(lhi * 16 + g * 4 + r) * 8] = (bf16)v;
        }
      }
    }
  }
}

// ---------------------------------------------------------------------------
// gemm2 r17: grid 4096, ONE 64-row m-tile per block (refill granularity).
// 512 thr = 8 waves x 32 n-cols. W2 B-frags register-resident; A from packed
// HP; T-transpose epilogue + fused LN. NT loads for Y0b, NT stores for Out.
// ---------------------------------------------------------------------------
__global__ __launch_bounds__(512) void gemm2_kernel(
    const bf16* __restrict__ HP, const bf16* __restrict__ W2P,
    const float* __restrict__ b2, const float* __restrict__ gamma,
    const float* __restrict__ beta, const float* __restrict__ Y0f,
    const bf16* __restrict__ Y0b, int useBf, float* __restrict__ Out) {
  __shared__ __align__(16) bf16 T[64 * 264];
  const int fid = blockIdx.x;      // 4096 blocks
  const int e = fid & 3;
  const int rr_ = fid >> 2;        // 0..1023
  const int t = rr_ & 15;
  const int mt = rr_ >> 4;         // 0..63
  const int tid = threadIdx.x, lane = tid & 63, w = tid >> 6;
  const int lr = lane & 15, g = lane >> 4;
  const int erow = tid >> 3, ec = tid & 7;
  const int b0 = mt * 64;

  bf16x8 breg[2][8];
  {
    const bf16* Wp = W2P + (((size_t)e * 256 + t * 16 + w * 2) * 8) * 512 +
                     lane * 8;
#pragma unroll
    for (int nj = 0; nj < 2; nj++)
#pragma unroll
      for (int kc = 0; kc < 8; kc++)
        breg[nj][kc] = *(const bf16x8*)&Wp[(size_t)(nj * 8 + kc) * 512];
  }
  float b2v[2];
#pragma unroll
  for (int nj = 0; nj < 2; nj++)
    b2v[nj] = b2[e * 4096 + t * 256 + w * 32 + nj * 16 + lr];

  const size_t ebase =
      (size_t)(b0 + erow) * 16384 + e * 4096 + t * 256 + ec * 32;

  // Y0 prefetch (read-once -> nontemporal)
  bf16x8 y0r[4];
  if (useBf) {
#pragma unroll
    for (int u = 0; u < 4; u++)
      y0r[u] = __builtin_nontemporal_load((const bf16x8*)&Y0b[ebase + u * 8]);
  }

  const bf16* Ap = HP + (((size_t)e * 256 + mt * 4) * 8) * 512 + lane * 8;
  f32x4 acc[4][2];
#pragma unroll
  for (int mf = 0; mf < 4; mf++)
#pragma unroll
    for (int nj = 0; nj < 2; nj++) acc[mf][nj] = zero4();

  bf16x8 afr[4], afn[4];
#pragma unroll
  for (int mf = 0; mf < 4; mf++)
    afr[mf] = *(const bf16x8*)&Ap[(size_t)(mf * 8) * 512];
#pragma unroll
  for (int kc = 0; kc < 8; kc++) {
    if (kc < 7) {
#pragma unroll
      for (int mf = 0; mf < 4; mf++)
        afn[mf] = *(const bf16x8*)&Ap[(size_t)(mf * 8 + kc + 1) * 512];
    }
#pragma unroll
    for (int mf = 0; mf < 4; mf++)
#pragma unroll
      for (int nj = 0; nj < 2; nj++)
        acc[mf][nj] = __builtin_amdgcn_mfma_f32_16x16x32_bf16(
            afr[mf], breg[nj][kc], acc[mf][nj], 0, 0, 0);
#pragma unroll
    for (int mf = 0; mf < 4; mf++) afr[mf] = afn[mf];
  }

  __syncthreads();
#pragma unroll
  for (int mf = 0; mf < 4; mf++)
#pragma unroll
    for (int nj = 0; nj < 2; nj++)
#pragma unroll
      for (int r = 0; r < 4; r++)
        T[(mf * 16 + g * 4 + r) * 264 + w * 32 + nj * 16 + lr] =
            (bf16)(acc[mf][nj][r] + b2v[nj]);
  __syncthreads();

  float y[4][8];
  float s1 = 0.f, s2 = 0.f;
#pragma unroll
  for (int u = 0; u < 4; u++) {
    bf16x8 tv = *(const bf16x8*)&T[erow * 264 + ec * 32 + u * 8];
    if (useBf) {
#pragma unroll
      for (int u8 = 0; u8 < 8; u8++) {
        float v = (float)tv[u8] + (float)y0r[u][u8];
        y[u][u8] = v;
        s1 += v;
        s2 += v * v;
      }
    } else {
      f32x4 a = *(const f32x4*)&Y0f[ebase + u * 8];
      f32x4 bb = *(const f32x4*)&Y0f[ebase + u * 8 + 4];
#pragma unroll
      for (int u8 = 0; u8 < 8; u8++) {
        float v = (float)tv[u8] + (u8 < 4 ? a[u8] : bb[u8 - 4]);
        y[u][u8] = v;
        s1 += v;
        s2 += v * v;
      }
    }
  }
  s1 += __shfl_xor(s1, 1); s1 += __shfl_xor(s1, 2); s1 += __shfl_xor(s1, 4);
  s2 += __shfl_xor(s2, 1); s2 += __shfl_xor(s2, 2); s2 += __shfl_xor(s2, 4);
  const float mu = s1 * (1.f / 256.f);
  const float var = s2 * (1.f / 256.f) - mu * mu;
  const float rs = rsqrtf(var + 1e-5f);

#pragma unroll
  for (int u = 0; u < 4; u++) {
    const int col = ec * 32 + u * 8;
    f32x4 gv0 = *(const f32x4*)&gamma[e * 256 + col];
    f32x4 gv1 = *(const f32x4*)&gamma[e * 256 + col + 4];
    f32x4 bt0 = *(const f32x4*)&beta[e * 256 + col];
    f32x4 bt1 = *(const f32x4*)&beta[e * 256 + col + 4];
    f32x4 o0, o1;
#pragma unroll
    for (int u8 = 0; u8 < 4; u8++) {
      o0[u8] = (y[u][u8] - mu) * rs * gv0[u8] + bt0[u8];
      o1[u8] = (y[u][u8 + 4] - mu) * rs * gv1[u8] + bt1[u8];
    }
    // Out is write-once, never re-read -> nontemporal (keep L3 for Y0b/W2P)
    __builtin_nontemporal_store(o0, (f32x4*)&Out[ebase + u * 8]);
    __builtin_nontemporal_store(o1, (f32x4*)&Out[ebase + u * 8 + 4]);
  }
}

// ---------------------------------------------------------------------------
extern "C" void kernel_launch(void* const* d_in, const int* in_sizes, int n_in,
                              void* d_out, int out_size, void* d_ws, size_t ws_size,
                              hipStream_t stream) {
  const float* X     = (const float*)d_in[0];
  const float* W1    = (const float*)d_in[1];
  const float* b1    = (const float*)d_in[2];
  const float* W2    = (const float*)d_in[3];
  const float* b2    = (const float*)d_in[4];
  const float* gamma = (const float*)d_in[5];
  const float* beta  = (const float*)d_in[6];
  float* Out = (float*)d_out;

  const size_t MB8 = (size_t)4 * 1048576;        // 4M bf16 elems = 8 MB
  bf16* W1P = (bf16*)d_ws;                       // 8 MB
  bf16* W2P = W1P + MB8;                         // 8 MB
  bf16* HP  = W2P + MB8;                         // 8 MB (fragment-packed H)
  bf16* Y0b = HP + MB8;                          // 134 MB

  const size_t bigN = (size_t)4096 * 16384 * 2;  // 134,217,728 B
  const size_t base = 3 * (MB8 * 2);             // 25,165,824 B
  const int useBf = (ws_size >= base + bigN) ? 1 : 0;

  pack_w1<<<dim3(4, 128, 4), dim3(256), 0, stream>>>(W1, W1P);
  pack_w2<<<dim3(8, 16, 4), dim3(256), 0, stream>>>(W2, W2P);
  fused_ag<<<dim3(4608), dim3(256), 0, stream>>>(X, W1P, b1, Out, Y0b, HP, useBf);
  gemm2_kernel<<<dim3(4096), dim3(512), 0, stream>>>(HP, W2P, b2, gamma, beta,
                                                     Out, Y0b, useBf, Out);
}

// Round 18
// 429.786 us; speedup vs baseline: 1.4206x; 1.4206x over previous
//
#include <hip/hip_runtime.h>

// GlobalInteraction r18: B=4096, N_GLOBAL=64, D=256, E=4, TPE=16, F=4096
// X:(B,64,256) f32; W1:(E,4096,256); b1:(E,256); W2:(E,256,4096); b2:(E,4096);
// gamma,beta:(E,256). Out:(B,64,256) f32.
//
// r18 = r17 with the nontemporal hints REVERTED (r17 post-mortem: NT stores
// defeated L2 write-combining, WRITE_SIZE 267->824 MB). Keeps gemm2 grid
// 4096 (one 64-row m-tile per block = refill granularity, the r16 lesson).
// fused_ag/packs: r16 verbatim.

typedef __attribute__((ext_vector_type(4))) float f32x4;
typedef __bf16 bf16;
typedef __attribute__((ext_vector_type(8))) bf16 bf16x8;
typedef __attribute__((ext_vector_type(4))) bf16 bf16x4;
typedef __attribute__((ext_vector_type(2))) bf16 bf16x2;

#define DEV static __device__ __forceinline__

DEV f32x4 zero4() { return f32x4{0.f, 0.f, 0.f, 0.f}; }

DEV bf16x8 cvt8(const f32x4& a, const f32x4& b) {
  bf16x8 o;
  o[0] = (bf16)a.x; o[1] = (bf16)a.y; o[2] = (bf16)a.z; o[3] = (bf16)a.w;
  o[4] = (bf16)b.x; o[5] = (bf16)b.y; o[6] = (bf16)b.z; o[7] = (bf16)b.w;
  return o;
}

// ---------------------------------------------------------------------------
// pack_w1: W1 (E,4096,256) f32 -> fragment-packed bf16.
// ---------------------------------------------------------------------------
__global__ __launch_bounds__(256) void pack_w1(const float* __restrict__ W1,
                                               bf16* __restrict__ P) {
  const int e = blockIdx.z, kc = blockIdx.y;
  const int nf = blockIdx.x * 4 + (threadIdx.x >> 6);
  const int l = threadIdx.x & 63;
  const float* src = W1 + (size_t)e * 4096 * 256 +
                     (size_t)(kc * 32 + (l >> 4) * 8) * 256 + nf * 16 + (l & 15);
  bf16x8 o;
#pragma unroll
  for (int j = 0; j < 8; j++) o[j] = (bf16)src[(size_t)j * 256];
  *(bf16x8*)&P[(((size_t)e * 128 + kc) * 16 + nf) * 512 + l * 8] = o;
}

// ---------------------------------------------------------------------------
// pack_w2: W2 (E,256,4096) f32 -> fragment-packed bf16.
// ---------------------------------------------------------------------------
__global__ __launch_bounds__(256) void pack_w2(const float* __restrict__ W2,
                                               bf16* __restrict__ P) {
  const int e = blockIdx.z, t = blockIdx.y, kc = blockIdx.x;
  const int l = threadIdx.x & 63;
#pragma unroll
  for (int it = 0; it < 4; it++) {
    int nfl = it * 4 + (threadIdx.x >> 6);
    const float* src = W2 + (size_t)e * 256 * 4096 +
                       (size_t)(kc * 32 + (l >> 4) * 8) * 4096 + t * 256 +
                       nfl * 16 + (l & 15);
    bf16x8 o;
#pragma unroll
    for (int j = 0; j < 8; j++) o[j] = (bf16)src[(size_t)j * 4096];
    *(bf16x8*)&P[(((size_t)e * 256 + t * 16 + nfl) * 8 + kc) * 512 + l * 8] = o;
  }
}

// ---------------------------------------------------------------------------
// fused_ag (r16): blocks 0-511 gemm1; blocks 512-4607 attention (1 pair/wave).
// ---------------------------------------------------------------------------
__global__ __launch_bounds__(256) void fused_ag(
    const float* __restrict__ X, const bf16* __restrict__ W1P,
    const float* __restrict__ b1, float* __restrict__ Y0f,
    bf16* __restrict__ Y0b, bf16* __restrict__ HP, int useBf) {
  __shared__ __align__(16) bf16 S[4 * 4608];   // 36,864 B
  __shared__ __align__(16) bf16 Plw[4 * 256];  //  2,048 B (P cols 0..15)
  __shared__ __align__(16) bf16 Zb[8];         //     16 B (zero k-pad)
  const int tid = threadIdx.x, lane = tid & 63, w = tid >> 6;
  const int lr = lane & 15, g = lane >> 4;
  const int fid = blockIdx.x;                  // 4608 blocks

  if (fid >= 512) {
    // ================= attention blocks: 1 pair per wave ==================
    bf16* xt = &S[w * 4608];
    bf16* plw = &Plw[w * 256];
    if (tid < 8) Zb[tid] = (bf16)0.f;
    __syncthreads();  // Zb visible to all waves
    const int koff = (g & 1) * 8;  // g>=2 lanes broadcast-read g&1's address

    const int p = (fid - 512) * 4 + w;         // pair id 0..16383
    const int b = p >> 2, e = p & 3;
    const size_t obase0 = (size_t)b * 16384 + e * 4096;
    const float* Xb = X + obase0;

    bf16x8 af[8];
#pragma unroll
    for (int c = 0; c < 8; c++) {
      const float* qq = Xb + lr * 256 + c * 32 + g * 8;
      f32x4 v0 = *(const f32x4*)qq;
      f32x4 v1 = *(const f32x4*)(qq + 4);
      bf16x8 o = cvt8(v0, v1);
      af[c] = o;
#pragma unroll
      for (int j = 0; j < 8; j++)
        xt[(c * 32 + g * 8 + j) * 18 + lr] = o[j];  // conflict-free
    }

    f32x4 s = zero4();
#pragma unroll
    for (int c = 0; c < 8; c++)
      s = __builtin_amdgcn_mfma_f32_16x16x32_bf16(af[c], af[c], s, 0, 0, 0);

    // softmax rows t=4g+r over m=lr; residual folded in: P' = P + I
    float pv[4];
#pragma unroll
    for (int r = 0; r < 4; r++) {
      float v = s[r] * 0.0625f;
      float mx = v;
#pragma unroll
      for (int mm = 1; mm < 16; mm <<= 1) mx = fmaxf(mx, __shfl_xor(mx, mm));
      float ev = __expf(v - mx);
      float sum = ev;
#pragma unroll
      for (int mm = 1; mm < 16; mm <<= 1) sum += __shfl_xor(sum, mm);
      pv[r] = ev / sum + ((lr == g * 4 + r) ? 1.0f : 0.0f);
    }
#pragma unroll
    for (int r = 0; r < 4; r++) plw[(g * 4 + r) * 16 + lr] = (bf16)pv[r];
    const bf16* psrc = (g < 2) ? &plw[lr * 16 + g * 8] : &Zb[0];
    bf16x8 pf = *(const bf16x8*)psrc;

    // PV: Y0 = (P+I) @ Xp
    float yo[16][4];
#pragma unroll
    for (int nc = 0; nc < 16; nc++) {
      const bf16* rowp = &xt[(nc * 16 + lr) * 18];
      bf16x8 bfr;
#pragma unroll
      for (int h = 0; h < 4; h++) {
        bf16x2 tv = *(const bf16x2*)&rowp[koff + h * 2];
        bfr[2 * h] = tv[0];
        bfr[2 * h + 1] = tv[1];
      }
      f32x4 xd =
          __builtin_amdgcn_mfma_f32_16x16x32_bf16(pf, bfr, zero4(), 0, 0, 0);
      yo[nc][0] = xd[0];
      yo[nc][1] = xd[1];
      yo[nc][2] = xd[2];
      yo[nc][3] = xd[3];
    }

    // transpose via LDS overlay Yl[16][268] (conflict-free scalar writes)
#pragma unroll
    for (int nc = 0; nc < 16; nc++)
#pragma unroll
      for (int r = 0; r < 4; r++)
        xt[(g * 4 + r) * 268 + nc * 16 + lr] = (bf16)yo[nc][r];

    const int tok = lane >> 2, cc = lane & 3;
    if (useBf) {
#pragma unroll
      for (int i = 0; i < 8; i++) {
        int d0 = i * 32 + cc * 8;
        bf16x4 v0 = *(const bf16x4*)&xt[tok * 268 + d0];
        bf16x4 v1 = *(const bf16x4*)&xt[tok * 268 + d0 + 4];
        bf16x8 v;
        v[0] = v0[0]; v[1] = v0[1]; v[2] = v0[2]; v[3] = v0[3];
        v[4] = v1[0]; v[5] = v1[1]; v[6] = v1[2]; v[7] = v1[3];
        *(bf16x8*)&Y0b[obase0 + tok * 256 + d0] = v;
      }
    } else {
#pragma unroll
      for (int i = 0; i < 8; i++) {
        int d0 = i * 32 + cc * 8;
        bf16x4 v0 = *(const bf16x4*)&xt[tok * 268 + d0];
        bf16x4 v1 = *(const bf16x4*)&xt[tok * 268 + d0 + 4];
        f32x4 a, bb;
        a.x = (float)v0[0]; a.y = (float)v0[1];
        a.z = (float)v0[2]; a.w = (float)v0[3];
        bb.x = (float)v1[0]; bb.y = (float)v1[1];
        bb.z = (float)v1[2]; bb.w = (float)v1[3];
        *(f32x4*)&Y0f[obase0 + tok * 256 + d0] = a;
        *(f32x4*)&Y0f[obase0 + tok * 256 + d0 + 4] = bb;
      }
    }
  } else {
    // ================= gemm1 blocks: M=32, BK=128, 4 waves =================
    const int sub = fid;                         // 0..511
    const int e = (sub & 7) >> 1;                // expert per XCD-pair
    const int m = ((sub >> 3) << 1) | (sub & 1); // 0..127
    const int b0 = m * 32;
    bf16* Ab0 = S;           // [32*136]
    bf16* Ab1 = S + 4352;    // [32*136]
    const int arow = tid >> 3, ak0 = (tid & 7) * 16;
    const size_t abase = (size_t)(b0 + arow) * 16384 + e * 4096 + ak0;
    const bf16* Wp = W1P + (size_t)e * 128 * 16 * 512;

    f32x4 acc[2][4];
#pragma unroll
    for (int i = 0; i < 2; i++)
#pragma unroll
      for (int j = 0; j < 4; j++) acc[i][j] = zero4();

    f32x4 p0, p1, p2, p3;
    {
      const float* q = X + abase;
      p0 = *(const f32x4*)q;       p1 = *(const f32x4*)(q + 4);
      p2 = *(const f32x4*)(q + 8); p3 = *(const f32x4*)(q + 12);
    }

    for (int kt = 0; kt < 32; kt++) {
      bf16* Ac = (kt & 1) ? Ab1 : Ab0;
      *(bf16x8*)&Ac[arow * 136 + ak0] = cvt8(p0, p1);
      *(bf16x8*)&Ac[arow * 136 + ak0 + 8] = cvt8(p2, p3);
      if (kt < 31) {
        const float* q = X + abase + (kt + 1) * 128;
        p0 = *(const f32x4*)q;       p1 = *(const f32x4*)(q + 4);
        p2 = *(const f32x4*)(q + 8); p3 = *(const f32x4*)(q + 12);
      }
      __syncthreads();  // block-uniform branch: all threads reach this
#pragma unroll
      for (int kki = 0; kki < 4; kki++) {
        const int kc = kt * 4 + kki;
        bf16x8 afr[2], bfr[4];
#pragma unroll
        for (int i = 0; i < 2; i++)
          afr[i] = *(const bf16x8*)&Ac[(i * 16 + lr) * 136 + kki * 32 + g * 8];
#pragma unroll
        for (int j = 0; j < 4; j++)
          bfr[j] = *(const bf16x8*)&Wp[(((size_t)kc) * 16 + w * 4 + j) * 512 +
                                       lane * 8];
#pragma unroll
        for (int i = 0; i < 2; i++)
#pragma unroll
          for (int j = 0; j < 4; j++)
            acc[i][j] = __builtin_amdgcn_mfma_f32_16x16x32_bf16(
                afr[i], bfr[j], acc[i][j], 0, 0, 0);
      }
    }
    // epilogue: relu(acc + b1) -> HP (fragment-packed)
#pragma unroll
    for (int j = 0; j < 4; j++) {
      const int col = w * 64 + j * 16 + lr;
      const float bv = b1[e * 256 + col];
      const int kc = col >> 5, lhi = (col >> 3) & 3, jj = col & 7;
#pragma unroll
      for (int i = 0; i < 2; i++) {
        const int mfg = m * 2 + i;
        bf16* dst = HP + (((size_t)e * 256 + mfg) * 8 + kc) * 512 + jj;
#pragma unroll
        for (int r = 0; r < 4; r++) {
          float v = fmaxf(acc[i][j][r] + bv, 0.f);
          dst[(lhi * 16 + g * 4 + r) * 8] = (bf16)v;
        }
      }
    }
  }
}

// ---------------------------------------------------------------------------
// gemm2 r18: grid 4096, ONE 64-row m-tile per block (refill granularity).
// 512 thr = 8 waves x 32 n-cols. W2 B-frags register-resident; A from packed
// HP; T-transpose epilogue + fused LN. Plain loads/stores (NT reverted).
// ---------------------------------------------------------------------------
__global__ __launch_bounds__(512) void gemm2_kernel(
    const bf16* __restrict__ HP, const bf16* __restrict__ W2P,
    const float* __restrict__ b2, const float* __restrict__ gamma,
    const float* __restrict__ beta, const float* __restrict__ Y0f,
    const bf16* __restrict__ Y0b, int useBf, float* __restrict__ Out) {
  __shared__ __align__(16) bf16 T[64 * 264];
  const int fid = blockIdx.x;      // 4096 blocks
  const int e = fid & 3;
  const int rr_ = fid >> 2;        // 0..1023
  const int t = rr_ & 15;
  const int mt = rr_ >> 4;         // 0..63
  const int tid = threadIdx.x, lane = tid & 63, w = tid >> 6;
  const int lr = lane & 15, g = lane >> 4;
  const int erow = tid >> 3, ec = tid & 7;
  const int b0 = mt * 64;

  bf16x8 breg[2][8];
  {
    const bf16* Wp = W2P + (((size_t)e * 256 + t * 16 + w * 2) * 8) * 512 +
                     lane * 8;
#pragma unroll
    for (int nj = 0; nj < 2; nj++)
#pragma unroll
      for (int kc = 0; kc < 8; kc++)
        breg[nj][kc] = *(const bf16x8*)&Wp[(size_t)(nj * 8 + kc) * 512];
  }
  float b2v[2];
#pragma unroll
  for (int nj = 0; nj < 2; nj++)
    b2v[nj] = b2[e * 4096 + t * 256 + w * 32 + nj * 16 + lr];

  const size_t ebase =
      (size_t)(b0 + erow) * 16384 + e * 4096 + t * 256 + ec * 32;

  // Y0 prefetch (overlaps MFMA phase)
  bf16x8 y0r[4];
  if (useBf) {
#pragma unroll
    for (int u = 0; u < 4; u++)
      y0r[u] = *(const bf16x8*)&Y0b[ebase + u * 8];
  }

  const bf16* Ap = HP + (((size_t)e * 256 + mt * 4) * 8) * 512 + lane * 8;
  f32x4 acc[4][2];
#pragma unroll
  for (int mf = 0; mf < 4; mf++)
#pragma unroll
    for (int nj = 0; nj < 2; nj++) acc[mf][nj] = zero4();

  bf16x8 afr[4], afn[4];
#pragma unroll
  for (int mf = 0; mf < 4; mf++)
    afr[mf] = *(const bf16x8*)&Ap[(size_t)(mf * 8) * 512];
#pragma unroll
  for (int kc = 0; kc < 8; kc++) {
    if (kc < 7) {
#pragma unroll
      for (int mf = 0; mf < 4; mf++)
        afn[mf] = *(const bf16x8*)&Ap[(size_t)(mf * 8 + kc + 1) * 512];
    }
#pragma unroll
    for (int mf = 0; mf < 4; mf++)
#pragma unroll
      for (int nj = 0; nj < 2; nj++)
        acc[mf][nj] = __builtin_amdgcn_mfma_f32_16x16x32_bf16(
            afr[mf], breg[nj][kc], acc[mf][nj], 0, 0, 0);
#pragma unroll
    for (int mf = 0; mf < 4; mf++) afr[mf] = afn[mf];
  }

  __syncthreads();
#pragma unroll
  for (int mf = 0; mf < 4; mf++)
#pragma unroll
    for (int nj = 0; nj < 2; nj++)
#pragma unroll
      for (int r = 0; r < 4; r++)
        T[(mf * 16 + g * 4 + r) * 264 + w * 32 + nj * 16 + lr] =
            (bf16)(acc[mf][nj][r] + b2v[nj]);
  __syncthreads();

  float y[4][8];
  float s1 = 0.f, s2 = 0.f;
#pragma unroll
  for (int u = 0; u < 4; u++) {
    bf16x8 tv = *(const bf16x8*)&T[erow * 264 + ec * 32 + u * 8];
    if (useBf) {
#pragma unroll
      for (int u8 = 0; u8 < 8; u8++) {
        float v = (float)tv[u8] + (float)y0r[u][u8];
        y[u][u8] = v;
        s1 += v;
        s2 += v * v;
      }
    } else {
      f32x4 a = *(const f32x4*)&Y0f[ebase + u * 8];
      f32x4 bb = *(const f32x4*)&Y0f[ebase + u * 8 + 4];
#pragma unroll
      for (int u8 = 0; u8 < 8; u8++) {
        float v = (float)tv[u8] + (u8 < 4 ? a[u8] : bb[u8 - 4]);
        y[u][u8] = v;
        s1 += v;
        s2 += v * v;
      }
    }
  }
  s1 += __shfl_xor(s1, 1); s1 += __shfl_xor(s1, 2); s1 += __shfl_xor(s1, 4);
  s2 += __shfl_xor(s2, 1); s2 += __shfl_xor(s2, 2); s2 += __shfl_xor(s2, 4);
  const float mu = s1 * (1.f / 256.f);
  const float var = s2 * (1.f / 256.f) - mu * mu;
  const float rs = rsqrtf(var + 1e-5f);

#pragma unroll
  for (int u = 0; u < 4; u++) {
    const int col = ec * 32 + u * 8;
    f32x4 gv0 = *(const f32x4*)&gamma[e * 256 + col];
    f32x4 gv1 = *(const f32x4*)&gamma[e * 256 + col + 4];
    f32x4 bt0 = *(const f32x4*)&beta[e * 256 + col];
    f32x4 bt1 = *(const f32x4*)&beta[e * 256 + col + 4];
    f32x4 o0, o1;
#pragma unroll
    for (int u8 = 0; u8 < 4; u8++) {
      o0[u8] = (y[u][u8] - mu) * rs * gv0[u8] + bt0[u8];
      o1[u8] = (y[u][u8 + 4] - mu) * rs * gv1[u8] + bt1[u8];
    }
    *(f32x4*)&Out[ebase + u * 8] = o0;
    *(f32x4*)&Out[ebase + u * 8 + 4] = o1;
  }
}

// ---------------------------------------------------------------------------
extern "C" void kernel_launch(void* const* d_in, const int* in_sizes, int n_in,
                              void* d_out, int out_size, void* d_ws, size_t ws_size,
                              hipStream_t stream) {
  const float* X     = (const float*)d_in[0];
  const float* W1    = (const float*)d_in[1];
  const float* b1    = (const float*)d_in[2];
  const float* W2    = (const float*)d_in[3];
  const float* b2    = (const float*)d_in[4];
  const float* gamma = (const float*)d_in[5];
  const float* beta  = (const float*)d_in[6];
  float* Out = (float*)d_out;

  const size_t MB8 = (size_t)4 * 1048576;        // 4M bf16 elems = 8 MB
  bf16* W1P = (bf16*)d_ws;                       // 8 MB
  bf16* W2P = W1P + MB8;                         // 8 MB
  bf16* HP  = W2P + MB8;                         // 8 MB (fragment-packed H)
  bf16* Y0b = HP + MB8;                          // 134 MB

  const size_t bigN = (size_t)4096 * 16384 * 2;  // 134,217,728 B
  const size_t base = 3 * (MB8 * 2);             // 25,165,824 B
  const int useBf = (ws_size >= base + bigN) ? 1 : 0;

  pack_w1<<<dim3(4, 128, 4), dim3(256), 0, stream>>>(W1, W1P);
  pack_w2<<<dim3(8, 16, 4), dim3(256), 0, stream>>>(W2, W2P);
  fused_ag<<<dim3(4608), dim3(256), 0, stream>>>(X, W1P, b1, Out, Y0b, HP, useBf);
  gemm2_kernel<<<dim3(4096), dim3(512), 0, stream>>>(HP, W2P, b2, gamma, beta,
                                                     Out, Y0b, useBf, Out);
}

// Round 19
// 346.612 us; speedup vs baseline: 1.7615x; 1.2400x over previous
//
#include <hip/hip_runtime.h>

// GlobalInteraction r19: B=4096, N_GLOBAL=64, D=256, E=4, TPE=16, F=4096
// X:(B,64,256) f32; W1:(E,4096,256); b1:(E,256); W2:(E,256,4096); b2:(E,4096);
// gamma,beta:(E,256). Out:(B,64,256) f32.
//
// r19 = fused_ag (r16: gemm1 blocks + 1-pair-per-wave attn blocks) +
// gemm2 reverted to the r6 structure (grid 512, block=(e,t,ms), W2 B-frags
// register-resident ONCE, loop 8 m-tiles) — the best-measured gemm2 (190us).
// Grid-size trend: gemm2 512>2048>4096 (breg amortization dominates refill).

typedef __attribute__((ext_vector_type(4))) float f32x4;
typedef __bf16 bf16;
typedef __attribute__((ext_vector_type(8))) bf16 bf16x8;
typedef __attribute__((ext_vector_type(4))) bf16 bf16x4;
typedef __attribute__((ext_vector_type(2))) bf16 bf16x2;

#define DEV static __device__ __forceinline__

DEV f32x4 zero4() { return f32x4{0.f, 0.f, 0.f, 0.f}; }

DEV bf16x8 cvt8(const f32x4& a, const f32x4& b) {
  bf16x8 o;
  o[0] = (bf16)a.x; o[1] = (bf16)a.y; o[2] = (bf16)a.z; o[3] = (bf16)a.w;
  o[4] = (bf16)b.x; o[5] = (bf16)b.y; o[6] = (bf16)b.z; o[7] = (bf16)b.w;
  return o;
}

// ---------------------------------------------------------------------------
// pack_w1: W1 (E,4096,256) f32 -> fragment-packed bf16.
// ---------------------------------------------------------------------------
__global__ __launch_bounds__(256) void pack_w1(const float* __restrict__ W1,
                                               bf16* __restrict__ P) {
  const int e = blockIdx.z, kc = blockIdx.y;
  const int nf = blockIdx.x * 4 + (threadIdx.x >> 6);
  const int l = threadIdx.x & 63;
  const float* src = W1 + (size_t)e * 4096 * 256 +
                     (size_t)(kc * 32 + (l >> 4) * 8) * 256 + nf * 16 + (l & 15);
  bf16x8 o;
#pragma unroll
  for (int j = 0; j < 8; j++) o[j] = (bf16)src[(size_t)j * 256];
  *(bf16x8*)&P[(((size_t)e * 128 + kc) * 16 + nf) * 512 + l * 8] = o;
}

// ---------------------------------------------------------------------------
// pack_w2: W2 (E,256,4096) f32 -> fragment-packed bf16.
// ---------------------------------------------------------------------------
__global__ __launch_bounds__(256) void pack_w2(const float* __restrict__ W2,
                                               bf16* __restrict__ P) {
  const int e = blockIdx.z, t = blockIdx.y, kc = blockIdx.x;
  const int l = threadIdx.x & 63;
#pragma unroll
  for (int it = 0; it < 4; it++) {
    int nfl = it * 4 + (threadIdx.x >> 6);
    const float* src = W2 + (size_t)e * 256 * 4096 +
                       (size_t)(kc * 32 + (l >> 4) * 8) * 4096 + t * 256 +
                       nfl * 16 + (l & 15);
    bf16x8 o;
#pragma unroll
    for (int j = 0; j < 8; j++) o[j] = (bf16)src[(size_t)j * 4096];
    *(bf16x8*)&P[(((size_t)e * 256 + t * 16 + nfl) * 8 + kc) * 512 + l * 8] = o;
  }
}

// ---------------------------------------------------------------------------
// fused_ag (r16): blocks 0-511 gemm1; blocks 512-4607 attention (1 pair/wave).
// ---------------------------------------------------------------------------
__global__ __launch_bounds__(256) void fused_ag(
    const float* __restrict__ X, const bf16* __restrict__ W1P,
    const float* __restrict__ b1, float* __restrict__ Y0f,
    bf16* __restrict__ Y0b, bf16* __restrict__ HP, int useBf) {
  __shared__ __align__(16) bf16 S[4 * 4608];   // 36,864 B
  __shared__ __align__(16) bf16 Plw[4 * 256];  //  2,048 B (P cols 0..15)
  __shared__ __align__(16) bf16 Zb[8];         //     16 B (zero k-pad)
  const int tid = threadIdx.x, lane = tid & 63, w = tid >> 6;
  const int lr = lane & 15, g = lane >> 4;
  const int fid = blockIdx.x;                  // 4608 blocks

  if (fid >= 512) {
    // ================= attention blocks: 1 pair per wave ==================
    bf16* xt = &S[w * 4608];
    bf16* plw = &Plw[w * 256];
    if (tid < 8) Zb[tid] = (bf16)0.f;
    __syncthreads();  // Zb visible to all waves
    const int koff = (g & 1) * 8;  // g>=2 lanes broadcast-read g&1's address

    const int p = (fid - 512) * 4 + w;         // pair id 0..16383
    const int b = p >> 2, e = p & 3;
    const size_t obase0 = (size_t)b * 16384 + e * 4096;
    const float* Xb = X + obase0;

    bf16x8 af[8];
#pragma unroll
    for (int c = 0; c < 8; c++) {
      const float* qq = Xb + lr * 256 + c * 32 + g * 8;
      f32x4 v0 = *(const f32x4*)qq;
      f32x4 v1 = *(const f32x4*)(qq + 4);
      bf16x8 o = cvt8(v0, v1);
      af[c] = o;
#pragma unroll
      for (int j = 0; j < 8; j++)
        xt[(c * 32 + g * 8 + j) * 18 + lr] = o[j];  // conflict-free
    }

    f32x4 s = zero4();
#pragma unroll
    for (int c = 0; c < 8; c++)
      s = __builtin_amdgcn_mfma_f32_16x16x32_bf16(af[c], af[c], s, 0, 0, 0);

    // softmax rows t=4g+r over m=lr; residual folded in: P' = P + I
    float pv[4];
#pragma unroll
    for (int r = 0; r < 4; r++) {
      float v = s[r] * 0.0625f;
      float mx = v;
#pragma unroll
      for (int mm = 1; mm < 16; mm <<= 1) mx = fmaxf(mx, __shfl_xor(mx, mm));
      float ev = __expf(v - mx);
      float sum = ev;
#pragma unroll
      for (int mm = 1; mm < 16; mm <<= 1) sum += __shfl_xor(sum, mm);
      pv[r] = ev / sum + ((lr == g * 4 + r) ? 1.0f : 0.0f);
    }
#pragma unroll
    for (int r = 0; r < 4; r++) plw[(g * 4 + r) * 16 + lr] = (bf16)pv[r];
    const bf16* psrc = (g < 2) ? &plw[lr * 16 + g * 8] : &Zb[0];
    bf16x8 pf = *(const bf16x8*)psrc;

    // PV: Y0 = (P+I) @ Xp
    float yo[16][4];
#pragma unroll
    for (int nc = 0; nc < 16; nc++) {
      const bf16* rowp = &xt[(nc * 16 + lr) * 18];
      bf16x8 bfr;
#pragma unroll
      for (int h = 0; h < 4; h++) {
        bf16x2 tv = *(const bf16x2*)&rowp[koff + h * 2];
        bfr[2 * h] = tv[0];
        bfr[2 * h + 1] = tv[1];
      }
      f32x4 xd =
          __builtin_amdgcn_mfma_f32_16x16x32_bf16(pf, bfr, zero4(), 0, 0, 0);
      yo[nc][0] = xd[0];
      yo[nc][1] = xd[1];
      yo[nc][2] = xd[2];
      yo[nc][3] = xd[3];
    }

    // transpose via LDS overlay Yl[16][268] (conflict-free scalar writes)
#pragma unroll
    for (int nc = 0; nc < 16; nc++)
#pragma unroll
      for (int r = 0; r < 4; r++)
        xt[(g * 4 + r) * 268 + nc * 16 + lr] = (bf16)yo[nc][r];

    const int tok = lane >> 2, cc = lane & 3;
    if (useBf) {
#pragma unroll
      for (int i = 0; i < 8; i++) {
        int d0 = i * 32 + cc * 8;
        bf16x4 v0 = *(const bf16x4*)&xt[tok * 268 + d0];
        bf16x4 v1 = *(const bf16x4*)&xt[tok * 268 + d0 + 4];
        bf16x8 v;
        v[0] = v0[0]; v[1] = v0[1]; v[2] = v0[2]; v[3] = v0[3];
        v[4] = v1[0]; v[5] = v1[1]; v[6] = v1[2]; v[7] = v1[3];
        *(bf16x8*)&Y0b[obase0 + tok * 256 + d0] = v;
      }
    } else {
#pragma unroll
      for (int i = 0; i < 8; i++) {
        int d0 = i * 32 + cc * 8;
        bf16x4 v0 = *(const bf16x4*)&xt[tok * 268 + d0];
        bf16x4 v1 = *(const bf16x4*)&xt[tok * 268 + d0 + 4];
        f32x4 a, bb;
        a.x = (float)v0[0]; a.y = (float)v0[1];
        a.z = (float)v0[2]; a.w = (float)v0[3];
        bb.x = (float)v1[0]; bb.y = (float)v1[1];
        bb.z = (float)v1[2]; bb.w = (float)v1[3];
        *(f32x4*)&Y0f[obase0 + tok * 256 + d0] = a;
        *(f32x4*)&Y0f[obase0 + tok * 256 + d0 + 4] = bb;
      }
    }
  } else {
    // ================= gemm1 blocks: M=32, BK=128, 4 waves =================
    const int sub = fid;                         // 0..511
    const int e = (sub & 7) >> 1;                // expert per XCD-pair
    const int m = ((sub >> 3) << 1) | (sub & 1); // 0..127
    const int b0 = m * 32;
    bf16* Ab0 = S;           // [32*136]
    bf16* Ab1 = S + 4352;    // [32*136]
    const int arow = tid >> 3, ak0 = (tid & 7) * 16;
    const size_t abase = (size_t)(b0 + arow) * 16384 + e * 4096 + ak0;
    const bf16* Wp = W1P + (size_t)e * 128 * 16 * 512;

    f32x4 acc[2][4];
#pragma unroll
    for (int i = 0; i < 2; i++)
#pragma unroll
      for (int j = 0; j < 4; j++) acc[i][j] = zero4();

    f32x4 p0, p1, p2, p3;
    {
      const float* q = X + abase;
      p0 = *(const f32x4*)q;       p1 = *(const f32x4*)(q + 4);
      p2 = *(const f32x4*)(q + 8); p3 = *(const f32x4*)(q + 12);
    }

    for (int kt = 0; kt < 32; kt++) {
      bf16* Ac = (kt & 1) ? Ab1 : Ab0;
      *(bf16x8*)&Ac[arow * 136 + ak0] = cvt8(p0, p1);
      *(bf16x8*)&Ac[arow * 136 + ak0 + 8] = cvt8(p2, p3);
      if (kt < 31) {
        const float* q = X + abase + (kt + 1) * 128;
        p0 = *(const f32x4*)q;       p1 = *(const f32x4*)(q + 4);
        p2 = *(const f32x4*)(q + 8); p3 = *(const f32x4*)(q + 12);
      }
      __syncthreads();  // block-uniform branch: all threads reach this
#pragma unroll
      for (int kki = 0; kki < 4; kki++) {
        const int kc = kt * 4 + kki;
        bf16x8 afr[2], bfr[4];
#pragma unroll
        for (int i = 0; i < 2; i++)
          afr[i] = *(const bf16x8*)&Ac[(i * 16 + lr) * 136 + kki * 32 + g * 8];
#pragma unroll
        for (int j = 0; j < 4; j++)
          bfr[j] = *(const bf16x8*)&Wp[(((size_t)kc) * 16 + w * 4 + j) * 512 +
                                       lane * 8];
#pragma unroll
        for (int i = 0; i < 2; i++)
#pragma unroll
          for (int j = 0; j < 4; j++)
            acc[i][j] = __builtin_amdgcn_mfma_f32_16x16x32_bf16(
                afr[i], bfr[j], acc[i][j], 0, 0, 0);
      }
    }
    // epilogue: relu(acc + b1) -> HP (fragment-packed)
#pragma unroll
    for (int j = 0; j < 4; j++) {
      const int col = w * 64 + j * 16 + lr;
      const float bv = b1[e * 256 + col];
      const int kc = col >> 5, lhi = (col >> 3) & 3, jj = col & 7;
#pragma unroll
      for (int i = 0; i < 2; i++) {
        const int mfg = m * 2 + i;
        bf16* dst = HP + (((size_t)e * 256 + mfg) * 8 + kc) * 512 + jj;
#pragma unroll
        for (int r = 0; r < 4; r++) {
          float v = fmaxf(acc[i][j][r] + bv, 0.f);
          dst[(lhi * 16 + g * 4 + r) * 8] = (bf16)v;
        }
      }
    }
  }
}

// ---------------------------------------------------------------------------
// gemm2 (r6 structure): grid 512, block=(e,t,ms); 512 thr = 8 waves x 32
// n-cols. W2 B-frags loaded ONCE into regs; loop 8 m-tiles: A from packed
// HP (1-deep kc pipeline), Y0 reg-prefetch, T-transpose epilogue + fused LN.
// ---------------------------------------------------------------------------
__global__ __launch_bounds__(512) void gemm2_kernel(
    const bf16* __restrict__ HP, const bf16* __restrict__ W2P,
    const float* __restrict__ b2, const float* __restrict__ gamma,
    const float* __restrict__ beta, const float* __restrict__ Y0f,
    const bf16* __restrict__ Y0b, int useBf, float* __restrict__ Out) {
  __shared__ __align__(16) bf16 T[64 * 264];
  const int fid = blockIdx.x;      // 512 blocks
  const int e = fid & 3;           // (e) pinned per XCD pair via fid&7
  const int rr_ = fid >> 2;        // 0..127
  const int t = rr_ & 15;
  const int ms = rr_ >> 4;         // 0..7
  const int tid = threadIdx.x, lane = tid & 63, w = tid >> 6;  // w 0..7
  const int lr = lane & 15, g = lane >> 4;
  const int erow = tid >> 3, ec = tid & 7;

  // resident B: wave w owns cols [w*32, w*32+32)
  bf16x8 breg[2][8];
  {
    const bf16* Wp = W2P + (((size_t)e * 256 + t * 16 + w * 2) * 8) * 512 +
                     lane * 8;
#pragma unroll
    for (int nj = 0; nj < 2; nj++)
#pragma unroll
      for (int kc = 0; kc < 8; kc++)
        breg[nj][kc] = *(const bf16x8*)&Wp[(size_t)(nj * 8 + kc) * 512];
  }
  float b2v[2];
#pragma unroll
  for (int nj = 0; nj < 2; nj++)
    b2v[nj] = b2[e * 4096 + t * 256 + w * 32 + nj * 16 + lr];

  for (int it = 0; it < 8; it++) {
    const int mt = ms * 8 + it;
    const int b0 = mt * 64;
    const size_t ebase =
        (size_t)(b0 + erow) * 16384 + e * 4096 + t * 256 + ec * 32;

    // Y0 prefetch (overlaps MFMA phase)
    bf16x8 y0r[4];
    if (useBf) {
#pragma unroll
      for (int u = 0; u < 4; u++)
        y0r[u] = *(const bf16x8*)&Y0b[ebase + u * 8];
    }

    // MFMA: A from HP, 1-deep kc pipeline
    const bf16* Ap = HP + (((size_t)e * 256 + mt * 4) * 8) * 512 + lane * 8;
    f32x4 acc[4][2];
#pragma unroll
    for (int mf = 0; mf < 4; mf++)
#pragma unroll
      for (int nj = 0; nj < 2; nj++) acc[mf][nj] = zero4();

    bf16x8 afr[4], afn[4];
#pragma unroll
    for (int mf = 0; mf < 4; mf++)
      afr[mf] = *(const bf16x8*)&Ap[(size_t)(mf * 8) * 512];
#pragma unroll
    for (int kc = 0; kc < 8; kc++) {
      if (kc < 7) {
#pragma unroll
        for (int mf = 0; mf < 4; mf++)
          afn[mf] = *(const bf16x8*)&Ap[(size_t)(mf * 8 + kc + 1) * 512];
      }
#pragma unroll
      for (int mf = 0; mf < 4; mf++)
#pragma unroll
        for (int nj = 0; nj < 2; nj++)
          acc[mf][nj] = __builtin_amdgcn_mfma_f32_16x16x32_bf16(
              afr[mf], breg[nj][kc], acc[mf][nj], 0, 0, 0);
#pragma unroll
      for (int mf = 0; mf < 4; mf++) afr[mf] = afn[mf];
    }

    __syncthreads();  // prior epilogue's T reads complete
#pragma unroll
    for (int mf = 0; mf < 4; mf++)
#pragma unroll
      for (int nj = 0; nj < 2; nj++)
#pragma unroll
        for (int r = 0; r < 4; r++)
          T[(mf * 16 + g * 4 + r) * 264 + w * 32 + nj * 16 + lr] =
              (bf16)(acc[mf][nj][r] + b2v[nj]);
    __syncthreads();

    // epilogue: thread owns row erow, cols [ec*32, ec*32+32)
    float y[4][8];
    float s1 = 0.f, s2 = 0.f;
#pragma unroll
    for (int u = 0; u < 4; u++) {
      bf16x8 tv = *(const bf16x8*)&T[erow * 264 + ec * 32 + u * 8];
      if (useBf) {
#pragma unroll
        for (int u8 = 0; u8 < 8; u8++) {
          float v = (float)tv[u8] + (float)y0r[u][u8];
          y[u][u8] = v;
          s1 += v;
          s2 += v * v;
        }
      } else {
        f32x4 a = *(const f32x4*)&Y0f[ebase + u * 8];
        f32x4 bb = *(const f32x4*)&Y0f[ebase + u * 8 + 4];
#pragma unroll
        for (int u8 = 0; u8 < 8; u8++) {
          float v = (float)tv[u8] + (u8 < 4 ? a[u8] : bb[u8 - 4]);
          y[u][u8] = v;
          s1 += v;
          s2 += v * v;
        }
      }
    }
    s1 += __shfl_xor(s1, 1); s1 += __shfl_xor(s1, 2); s1 += __shfl_xor(s1, 4);
    s2 += __shfl_xor(s2, 1); s2 += __shfl_xor(s2, 2); s2 += __shfl_xor(s2, 4);
    const float mu = s1 * (1.f / 256.f);
    const float var = s2 * (1.f / 256.f) - mu * mu;
    const float rs = rsqrtf(var + 1e-5f);

#pragma unroll
    for (int u = 0; u < 4; u++) {
      const int col = ec * 32 + u * 8;
      f32x4 gv0 = *(const f32x4*)&gamma[e * 256 + col];
      f32x4 gv1 = *(const f32x4*)&gamma[e * 256 + col + 4];
      f32x4 bt0 = *(const f32x4*)&beta[e * 256 + col];
      f32x4 bt1 = *(const f32x4*)&beta[e * 256 + col + 4];
      f32x4 o0, o1;
#pragma unroll
      for (int u8 = 0; u8 < 4; u8++) {
        o0[u8] = (y[u][u8] - mu) * rs * gv0[u8] + bt0[u8];
        o1[u8] = (y[u][u8 + 4] - mu) * rs * gv1[u8] + bt1[u8];
      }
      *(f32x4*)&Out[ebase + u * 8] = o0;
      *(f32x4*)&Out[ebase + u * 8 + 4] = o1;
    }
  }
}

// ---------------------------------------------------------------------------
extern "C" void kernel_launch(void* const* d_in, const int* in_sizes, int n_in,
                              void* d_out, int out_size, void* d_ws, size_t ws_size,
                              hipStream_t stream) {
  const float* X     = (const float*)d_in[0];
  const float* W1    = (const float*)d_in[1];
  const float* b1    = (const float*)d_in[2];
  const float* W2    = (const float*)d_in[3];
  const float* b2    = (const float*)d_in[4];
  const float* gamma = (const float*)d_in[5];
  const float* beta  = (const float*)d_in[6];
  float* Out = (float*)d_out;

  const size_t MB8 = (size_t)4 * 1048576;        // 4M bf16 elems = 8 MB
  bf16* W1P = (bf16*)d_ws;                       // 8 MB
  bf16* W2P = W1P + MB8;                         // 8 MB
  bf16* HP  = W2P + MB8;                         // 8 MB (fragment-packed H)
  bf16* Y0b = HP + MB8;                          // 134 MB

  const size_t bigN = (size_t)4096 * 16384 * 2;  // 134,217,728 B
  const size_t base = 3 * (MB8 * 2);             // 25,165,824 B
  const int useBf = (ws_size >= base + bigN) ? 1 : 0;

  pack_w1<<<dim3(4, 128, 4), dim3(256), 0, stream>>>(W1, W1P);
  pack_w2<<<dim3(8, 16, 4), dim3(256), 0, stream>>>(W2, W2P);
  fused_ag<<<dim3(4608), dim3(256), 0, stream>>>(X, W1P, b1, Out, Y0b, HP, useBf);
  gemm2_kernel<<<dim3(512), dim3(512), 0, stream>>>(HP, W2P, b2, gamma, beta,
                                                    Out, Y0b, useBf, Out);
}